// Round 17
// baseline (210.486 us; speedup 1.0000x reference)
//
#include <hip/hip_runtime.h>
#include <hip/hip_bf16.h>
#include <math.h>

#define B_ 4
#define N_ 2048
#define C_ 768
#define H_ 12
#define D_ 64
#define SC_LOG2E 0.18033688f   // 0.125 * log2(e), folded into stored Q

typedef __attribute__((ext_vector_type(8))) short bf16x8;
typedef __attribute__((ext_vector_type(4))) short bf16x4;
typedef __attribute__((ext_vector_type(4))) float f32x4;

#define MFMA16(A, B, C) __builtin_amdgcn_mfma_f32_16x16x32_bf16(A, B, C, 0, 0, 0)

// 16x16x16 bf16 MFMA: A/B are 4 bf16 per lane (k = quad*4 + j).
#if __has_builtin(__builtin_amdgcn_mfma_f32_16x16x16bf16_1k)
#define MFMA16K16(A, B, C) __builtin_amdgcn_mfma_f32_16x16x16bf16_1k(A, B, C, 0, 0, 0)
#else
__device__ __forceinline__ f32x4 mfma16k16_asm(bf16x4 a, bf16x4 b, f32x4 c) {
    f32x4 d;
    asm("v_mfma_f32_16x16x16_bf16 %0, %1, %2, %3"
        : "=v"(d) : "v"(a), "v"(b), "v"(c));
    return d;
}
#define MFMA16K16(A, B, C) mfma16k16_asm(A, B, C)
#endif

#if __has_builtin(__builtin_amdgcn_exp2f)
#define EXP2F(x) __builtin_amdgcn_exp2f(x)
#else
#define EXP2F(x) exp2f(x)
#endif

__device__ __forceinline__ ushort f2bf(float f) {
    union { float f; unsigned u; } v; v.f = f;
    unsigned r = v.u + 0x7fffu + ((v.u >> 16) & 1u);   // RNE
    return (ushort)(r >> 16);
}

#if __has_builtin(__builtin_amdgcn_cvt_pk_bf16_f32)
typedef __attribute__((ext_vector_type(2))) __bf16 bf16x2v;
__device__ __forceinline__ unsigned pack_bf2(float a, float b) {
    union { bf16x2v v; unsigned u; } cv;
    cv.v = __builtin_amdgcn_cvt_pk_bf16_f32(a, b);
    return cv.u;
}
#else
__device__ __forceinline__ unsigned pack_bf2(float a, float b) {
    union { __hip_bfloat162 h2; unsigned u; } cv;
    cv.h2 = __float22bfloat162_rn(make_float2(a, b));
    return cv.u;
}
#endif

// async global->LDS, 16B per lane; lds base wave-uniform, lane i -> base+i*16B.
__device__ __forceinline__ void gl_lds16(const ushort* g, ushort* l) {
    __builtin_amdgcn_global_load_lds(
        (const __attribute__((address_space(1))) unsigned*)g,
        (__attribute__((address_space(3))) unsigned*)l, 16, 0, 0);
}

// ---------- fused prep: x cvt + Wqkv transpose + Wproj transpose ----------
__device__ __forceinline__ void tr_body(const float* __restrict__ W,
                                        ushort* __restrict__ Wt,
                                        int K, int N, int bx, int by, int t) {
    __shared__ float T[32][33];
    int k0 = by * 32, n0 = bx * 32;
    int r = t >> 3, c4 = (t & 7) * 4;
    float4 v = *(const float4*)&W[(size_t)(k0 + r) * N + n0 + c4];
    T[r][c4] = v.x; T[r][c4 + 1] = v.y; T[r][c4 + 2] = v.z; T[r][c4 + 3] = v.w;
    __syncthreads();
    union { ushort s[4]; unsigned long long u; } o;
    o.s[0] = f2bf(T[c4 + 0][r]);
    o.s[1] = f2bf(T[c4 + 1][r]);
    o.s[2] = f2bf(T[c4 + 2][r]);
    o.s[3] = f2bf(T[c4 + 3][r]);
    *(unsigned long long*)&Wt[(size_t)(n0 + r) * K + k0 + c4] = o.u;
}

__global__ __launch_bounds__(256) void prep(
    const float* __restrict__ x, ushort* __restrict__ xb,
    const float* __restrict__ Wqkv, ushort* __restrict__ Wqkvt,
    const float* __restrict__ Wproj, ushort* __restrict__ Wprojt)
{
    const int bid = blockIdx.x, t = threadIdx.x;
    if (bid < 3072) {
        int i = bid * 256 + t;
        const float4* p = (const float4*)x + 2 * (size_t)i;
        float4 a = p[0], bq = p[1];
        union { ushort s[8]; uint4 v; } u;
        u.s[0] = f2bf(a.x);  u.s[1] = f2bf(a.y);  u.s[2] = f2bf(a.z);  u.s[3] = f2bf(a.w);
        u.s[4] = f2bf(bq.x); u.s[5] = f2bf(bq.y); u.s[6] = f2bf(bq.z); u.s[7] = f2bf(bq.w);
        *(uint4*)&xb[(size_t)i * 8] = u.v;
    } else if (bid < 4800) {
        int id = bid - 3072;                    // 72 x 24
        tr_body(Wqkv, Wqkvt, C_, 3 * C_, id % 72, id / 72, t);
    } else {
        int id = bid - 4800;                    // 24 x 24
        tr_body(Wproj, Wprojt, C_, C_, id % 24, id / 24, t);
    }
}

// ---------- bf16 MFMA GEMM: A[M][K] bf16, Bt[N][K] bf16, +bias ----------
// Tile 128(M) x TN(N), BK=64 single-buffered, 4 waves each 64 x TN/2.
// TN=192 for the QKV GEMM: grid = 12x64 = 768 blocks = exactly 3/CU, all
// co-resident, no straggler tail (measured WIN R16: total 225->210 us).
// launch_bounds(256,3) caps VGPR at 170 so 3 blocks/CU fit. TN=128 for the
// proj GEMM (measured: its balance doesn't matter). XCD-aware swizzle.
// OBF (qkv path): bf16 output, q-zone cols scaled by SC_LOG2E; v-zone cols
// (col0 >= 2C) are written TRANSPOSED per head into vtp[bh][d][tok].
template <bool OBF, int TN>
__global__ __launch_bounds__(256, 3) void gemm_bf16(
    const ushort* __restrict__ A, const ushort* __restrict__ Bt,
    const float* __restrict__ bias, void* __restrict__ outp,
    ushort* __restrict__ vtp,
    int M, int N, int K)
{
    constexpr int NTC = TN / 32;          // nt-count per wave (6 or 4)
    __shared__ ushort Asl[128 * 64];
    __shared__ ushort Bsl[TN * 64];

    const int tid  = threadIdx.x;
    const int lane = tid & 63, w = tid >> 6;
    const int quad = lane >> 4, l16 = lane & 15;

    // XCD swizzle: nwg % 8 == 0 for all launches (768, 384).
    const int nx   = gridDim.x;
    const int flat = blockIdx.y * nx + blockIdx.x;
    const int cpx  = (nx * gridDim.y) >> 3;
    const int nf   = (flat & 7) * cpx + (flat >> 3);
    const int row0 = (nf / nx) * 128, col0 = (nf % nx) * TN;
    const int mh = (w >> 1) * 64, nh = (w & 1) * (TN / 2);

    f32x4 acc[4][NTC];
#pragma unroll
    for (int i = 0; i < 4; i++)
#pragma unroll
        for (int j = 0; j < NTC; j++) acc[i][j] = (f32x4)0.f;

    for (int k0 = 0; k0 < K; k0 += 64) {
#pragma unroll
        for (int i = 0; i < 4; i++) {       // A: 1024 chunks
            int c  = i * 256 + w * 64 + lane;
            int rr = c >> 3;
            int cc = (c & 7) ^ (rr & 7);
            gl_lds16(&A[(size_t)(row0 + rr) * K + k0 + cc * 8], &Asl[c * 8]);
        }
#pragma unroll
        for (int i = 0; i < NTC; i++) {     // B: TN*8 chunks
            int c  = i * 256 + w * 64 + lane;
            int rr = c >> 3;
            int cc = (c & 7) ^ (rr & 7);
            gl_lds16(&Bt[(size_t)(col0 + rr) * K + k0 + cc * 8], &Bsl[c * 8]);
        }
        __syncthreads();
#pragma unroll
        for (int h = 0; h < 2; h++) {
            const int sw = ((h * 4 + quad) ^ (l16 & 7)) * 8;
            bf16x8 af[4], bfr[NTC];
#pragma unroll
            for (int mt = 0; mt < 4; mt++)
                af[mt] = *(const bf16x8*)&Asl[(mh + mt * 16 + l16) * 64 + sw];
#pragma unroll
            for (int nt = 0; nt < NTC; nt++)
                bfr[nt] = *(const bf16x8*)&Bsl[(nh + nt * 16 + l16) * 64 + sw];
#pragma unroll
            for (int mt = 0; mt < 4; mt++)
#pragma unroll
                for (int nt = 0; nt < NTC; nt++)
                    acc[mt][nt] = MFMA16(af[mt], bfr[nt], acc[mt][nt]);
        }
        __syncthreads();
    }

    if (OBF && col0 >= 2 * C_) {
        // v-zone: write transposed into Vt[bh][d][tok]
#pragma unroll
        for (int nt = 0; nt < NTC; nt++) {
            int colh = col0 - 2 * C_ + nh + nt * 16 + l16;   // 0..767
            int hh = colh >> 6, dd = colh & 63;
            float bv = bias[col0 + nh + nt * 16 + l16];
#pragma unroll
            for (int mt = 0; mt < 4; mt++) {
                f32x4 v = acc[mt][nt];
                int row = row0 + mh + mt * 16 + quad * 4;
                int bb = row >> 11, tok = row & (N_ - 1);
                union { ushort us[4]; unsigned long long u; } o;
#pragma unroll
                for (int r = 0; r < 4; r++) o.us[r] = f2bf(v[r] + bv);
                *(unsigned long long*)&vtp[((size_t)(bb * H_ + hh) * D_ + dd) * N_ + tok] = o.u;
            }
        }
    } else {
        const float scl = (OBF && col0 < C_) ? SC_LOG2E : 1.f;
#pragma unroll
        for (int nt = 0; nt < NTC; nt++) {
            int col = col0 + nh + nt * 16 + l16;
            float bv = bias[col];
#pragma unroll
            for (int mt = 0; mt < 4; mt++) {
                f32x4 v = acc[mt][nt];
#pragma unroll
                for (int r = 0; r < 4; r++) {
                    int row = row0 + mh + mt * 16 + quad * 4 + r;
                    if (OBF)
                        ((ushort*)outp)[(size_t)row * N + col] = f2bf((v[r] + bv) * scl);
                    else
                        ((float*)outp)[(size_t)row * N + col] = v[r] + bv;
                }
            }
        }
    }
}

// ---------- MFMA flash attention: 8 waves x 16 q, reg-P, triple-buffered ----------
// Measured best body (R12/R16: 80-84 us). NEW: vectorized epilogue — after
// the loop's final vmcnt(0)+barrier, Kd/Vd are dead for ALL waves; each wave
// transposes its 16q x 64d O-tile through that LDS and stores 2 coalesced
// uint4 per thread instead of 16 scalar 2-byte stores (Common-mistake #2).
__global__ __launch_bounds__(512, 6) void attn_mfma(
    const ushort* __restrict__ qkvb, const ushort* __restrict__ Vt,
    ushort* __restrict__ attnb)
{
    __shared__ ushort Kd[3][64 * 64];     // [key][d], swizzled 16B chunks
    __shared__ ushort Vd[3][64 * 64];     // [d][key], swizzled 16B chunks

    const int tid  = threadIdx.x;
    const int lane = tid & 63, w = tid >> 6;      // w = 0..7
    const int quad = lane >> 4, l16 = lane & 15;

    // XCD-aware remap (bijective: 768 % 8 == 0): each XCD gets 6 whole
    // heads (3 MB K/V working set, L2-resident).
    const int flat = blockIdx.y * 16 + blockIdx.x;
    const int nf   = (flat & 7) * 96 + (flat >> 3);
    const int bh   = nf >> 4, qt_ = nf & 15;
    const int b = bh / H_, h = bh % H_;
    const int q0 = qt_ * 128 + w * 16;
    const size_t rowbase = (size_t)b * N_;
    const int hoff = h * D_;
    const f32x4 Z4 = {0.f, 0.f, 0.f, 0.f};

    const ushort* Kg = qkvb + rowbase * (3 * C_) + C_ + hoff;  // + tok*(3C)
    const ushort* Vg = Vt + (size_t)bh * D_ * N_;              // + d*N_ + tok

    // staging: 512 threads cover the 512 16B-chunks of one 64x64 tile
    const int rr = tid >> 3;                  // row 0..63
    const int cc = (tid & 7) ^ (rr & 7);      // pre-swizzled chunk
    const int wbase = w * 512;                // wave-uniform LDS base (ushorts)
    const ushort* kp = Kg + (size_t)rr * (3 * C_) + cc * 8;
    const ushort* vp = Vg + (size_t)rr * N_ + cc * 8;

    bf16x8 Qf[2];
#pragma unroll
    for (int c = 0; c < 2; c++)
        Qf[c] = *(const bf16x8*)&qkvb[(rowbase + q0 + l16) * (3 * C_)
                                      + hoff + c * 32 + quad * 8];

    f32x4 oacc[4];
#pragma unroll
    for (int nt = 0; nt < 4; nt++) oacc[nt] = (f32x4)0.f;
    float lrow = 0.f;

    const int NT = N_ / 64;   // 32 tiles
    // prologue: stage tiles 0 and 1
    gl_lds16(kp, &Kd[0][wbase]);
    gl_lds16(vp, &Vd[0][wbase]);
    kp += (size_t)64 * 3 * C_; vp += 64;
    gl_lds16(kp, &Kd[1][wbase]);
    gl_lds16(vp, &Vd[1][wbase]);
    kp += (size_t)64 * 3 * C_; vp += 64;
    asm volatile("s_waitcnt vmcnt(2)" ::: "memory");   // tile 0 landed (mine)
    __builtin_amdgcn_s_barrier();                      // ...and everyone's
    __builtin_amdgcn_sched_barrier(0);

    int rd = 0;                                // read buffer = t % 3
    for (int t = 0; t < NT; ++t) {
        int wr = rd + 2; if (wr >= 3) wr -= 3; // (t+2) % 3
        if (t + 2 < NT) {
            gl_lds16(kp, &Kd[wr][wbase]);
            gl_lds16(vp, &Vd[wr][wbase]);
            kp += (size_t)64 * 3 * C_; vp += 64;
        }
        __builtin_amdgcn_sched_barrier(0);     // keep the issues early

        const ushort* Kb = Kd[rd];
        const ushort* Vb = Vd[rd];

        // QK^T: sacc[kt], lane holds P[key=kt*16+quad*4+r][q=l16]
        f32x4 sacc[4];
        {
            bf16x8 kf[4];
#pragma unroll
            for (int kt = 0; kt < 4; kt++)
                kf[kt] = *(const bf16x8*)&Kb[(kt * 16 + l16) * 64
                                             + ((quad) ^ (l16 & 7)) * 8];
            __builtin_amdgcn_s_setprio(1);
#pragma unroll
            for (int kt = 0; kt < 4; kt++)
                sacc[kt] = MFMA16(kf[kt], Qf[0], Z4);
            __builtin_amdgcn_s_setprio(0);
        }
        {
            bf16x8 kf[4];
#pragma unroll
            for (int kt = 0; kt < 4; kt++)
                kf[kt] = *(const bf16x8*)&Kb[(kt * 16 + l16) * 64
                                             + ((4 | quad) ^ (l16 & 7)) * 8];
            __builtin_amdgcn_s_setprio(1);
#pragma unroll
            for (int kt = 0; kt < 4; kt++)
                sacc[kt] = MFMA16(kf[kt], Qf[1], sacc[kt]);
            __builtin_amdgcn_s_setprio(0);
        }

        // softmax numerator -> packed bf16 pairs, kept in registers
        unsigned pkx[4], pky[4];
        {
            float sum = 0.f;
#pragma unroll
            for (int kt = 0; kt < 4; kt++) {
                float p0 = EXP2F(sacc[kt][0]);
                float p1 = EXP2F(sacc[kt][1]);
                float p2 = EXP2F(sacc[kt][2]);
                float p3 = EXP2F(sacc[kt][3]);
                sum += (p0 + p1) + (p2 + p3);
                pkx[kt] = pack_bf2(p0, p1);
                pky[kt] = pack_bf2(p2, p3);
            }
            lrow += sum;
        }

        // PV via 16x16x16: A = packed P (reg-direct), B = V^T 4-key b64.
        // out: lane holds O[q=quad*4+r][d=nt*16+l16] accumulated in oacc[nt].
        __builtin_amdgcn_s_setprio(1);
#pragma unroll
        for (int kt = 0; kt < 4; kt++) {
            union { unsigned u[2]; bf16x4 s; } av;
            av.u[0] = pkx[kt]; av.u[1] = pky[kt];
            const int ch = ((kt * 2 + (quad >> 1)) ^ (l16 & 7));
#pragma unroll
            for (int nt = 0; nt < 4; nt++) {
                bf16x4 vb = *(const bf16x4*)&Vb[(nt * 16 + l16) * 64
                                                + ch * 8 + (quad & 1) * 4];
                oacc[nt] = MFMA16K16(av.s, vb, oacc[nt]);
            }
        }
        __builtin_amdgcn_s_setprio(0);

        // counted wait: my t+1 loads have landed; t+2 stays in flight.
        if (t < NT - 2) asm volatile("s_waitcnt vmcnt(2)" ::: "memory");
        else            asm volatile("s_waitcnt vmcnt(0)" ::: "memory");
        __builtin_amdgcn_s_barrier();
        __builtin_amdgcn_sched_barrier(0);
        rd++; if (rd == 3) rd = 0;
    }

    // ---- epilogue: O-tile transpose through dead Kd/Vd, coalesced stores ----
    // Loop ended with vmcnt(0)+s_barrier: every wave is past its last K/V
    // read, so Kd/Vd are dead block-wide. Per-wave 16q x 64d f32 scratch
    // (4 KB): waves 0-5 in Kd (24 KB), waves 6-7 in Vd. Same-wave LDS
    // write->read ordering via lgkmcnt only.
    {
        float s = lrow;
        s += __shfl_xor(s, 16, 64);
        s += __shfl_xor(s, 32, 64);          // lane L: denom for q = L&15
        float invq[4];
#pragma unroll
        for (int r = 0; r < 4; r++)
            invq[r] = 1.f / __shfl(s, quad * 4 + r, 64);

        float* pw = (w < 6) ? (float*)&Kd[0][0] + w * 1024
                            : (float*)&Vd[0][0] + (w - 6) * 1024;
#pragma unroll
        for (int nt = 0; nt < 4; nt++)
#pragma unroll
            for (int r = 0; r < 4; r++)
                pw[(quad * 4 + r) * 64 + nt * 16 + l16] = oacc[nt][r] * invq[r];

        asm volatile("s_waitcnt lgkmcnt(0)" ::: "memory");
        __builtin_amdgcn_sched_barrier(0);

#pragma unroll
        for (int half = 0; half < 2; half++) {
            int q  = (lane >> 3) + half * 8;     // 0..15
            int d0 = (lane & 7) * 8;             // 0,8,..,56
            union { ushort us[8]; uint4 v; } o;
#pragma unroll
            for (int j = 0; j < 8; j++) o.us[j] = f2bf(pw[q * 64 + d0 + j]);
            *(uint4*)&attnb[(rowbase + q0 + q) * C_ + hoff + d0] = o.v;
        }
    }
}

// ---------------- launcher ----------------
extern "C" void kernel_launch(void* const* d_in, const int* in_sizes, int n_in,
                              void* d_out, int out_size, void* d_ws, size_t ws_size,
                              hipStream_t stream)
{
    const float* x     = (const float*)d_in[0];
    const float* Wqkv  = (const float*)d_in[1];
    const float* bqkv  = (const float*)d_in[2];
    const float* Wproj = (const float*)d_in[3];
    const float* bproj = (const float*)d_in[4];

    ushort* xb     = (ushort*)d_ws;                                    // [8192][768]
    ushort* Wqkvt  = xb + (size_t)B_ * N_ * C_;                        // [2304][768]
    ushort* Wprojt = Wqkvt + (size_t)3 * C_ * C_;                      // [768][768]
    ushort* qkvb   = Wprojt + (size_t)C_ * C_;                         // [8192][2304]
    ushort* attnb  = qkvb + (size_t)B_ * N_ * 3 * C_;                  // [8192][768]
    ushort* Vtb    = attnb + (size_t)B_ * N_ * C_;                     // [48][64][2048]

    const int M = B_ * N_;

    prep<<<5376, 256, 0, stream>>>(x, xb, Wqkv, Wqkvt, Wproj, Wprojt);

    gemm_bf16<true, 192><<<dim3((3 * C_) / 192, M / 128), 256, 0, stream>>>(
        xb, Wqkvt, bqkv, qkvb, Vtb, M, 3 * C_, C_);

    attn_mfma<<<dim3(N_ / 128, B_ * H_), 512, 0, stream>>>(qkvb, Vtb, attnb);

    gemm_bf16<false, 128><<<dim3(C_ / 128, M / 128), 256, 0, stream>>>(
        attnb, Wprojt, bproj, d_out, nullptr, M, C_, C_);
}

// Round 18
// 207.502 us; speedup vs baseline: 1.0144x; 1.0144x over previous
//
#include <hip/hip_runtime.h>
#include <hip/hip_bf16.h>
#include <math.h>

#define B_ 4
#define N_ 2048
#define C_ 768
#define H_ 12
#define D_ 64
#define SC_LOG2E 0.18033688f   // 0.125 * log2(e), folded into stored Q

typedef __attribute__((ext_vector_type(8))) short bf16x8;
typedef __attribute__((ext_vector_type(4))) short bf16x4;
typedef __attribute__((ext_vector_type(4))) float f32x4;

#define MFMA16(A, B, C) __builtin_amdgcn_mfma_f32_16x16x32_bf16(A, B, C, 0, 0, 0)

// 16x16x16 bf16 MFMA: A/B are 4 bf16 per lane (k = quad*4 + j).
#if __has_builtin(__builtin_amdgcn_mfma_f32_16x16x16bf16_1k)
#define MFMA16K16(A, B, C) __builtin_amdgcn_mfma_f32_16x16x16bf16_1k(A, B, C, 0, 0, 0)
#else
__device__ __forceinline__ f32x4 mfma16k16_asm(bf16x4 a, bf16x4 b, f32x4 c) {
    f32x4 d;
    asm("v_mfma_f32_16x16x16_bf16 %0, %1, %2, %3"
        : "=v"(d) : "v"(a), "v"(b), "v"(c));
    return d;
}
#define MFMA16K16(A, B, C) mfma16k16_asm(A, B, C)
#endif

#if __has_builtin(__builtin_amdgcn_exp2f)
#define EXP2F(x) __builtin_amdgcn_exp2f(x)
#else
#define EXP2F(x) exp2f(x)
#endif

__device__ __forceinline__ ushort f2bf(float f) {
    union { float f; unsigned u; } v; v.f = f;
    unsigned r = v.u + 0x7fffu + ((v.u >> 16) & 1u);   // RNE
    return (ushort)(r >> 16);
}

#if __has_builtin(__builtin_amdgcn_cvt_pk_bf16_f32)
typedef __attribute__((ext_vector_type(2))) __bf16 bf16x2v;
__device__ __forceinline__ unsigned pack_bf2(float a, float b) {
    union { bf16x2v v; unsigned u; } cv;
    cv.v = __builtin_amdgcn_cvt_pk_bf16_f32(a, b);
    return cv.u;
}
#else
__device__ __forceinline__ unsigned pack_bf2(float a, float b) {
    union { __hip_bfloat162 h2; unsigned u; } cv;
    cv.h2 = __float22bfloat162_rn(make_float2(a, b));
    return cv.u;
}
#endif

// async global->LDS, 16B per lane; lds base wave-uniform, lane i -> base+i*16B.
__device__ __forceinline__ void gl_lds16(const ushort* g, ushort* l) {
    __builtin_amdgcn_global_load_lds(
        (const __attribute__((address_space(1))) unsigned*)g,
        (__attribute__((address_space(3))) unsigned*)l, 16, 0, 0);
}

// ---------- fused prep: x cvt + Wqkv transpose + Wproj transpose ----------
__device__ __forceinline__ void tr_body(const float* __restrict__ W,
                                        ushort* __restrict__ Wt,
                                        int K, int N, int bx, int by, int t) {
    __shared__ float T[32][33];
    int k0 = by * 32, n0 = bx * 32;
    int r = t >> 3, c4 = (t & 7) * 4;
    float4 v = *(const float4*)&W[(size_t)(k0 + r) * N + n0 + c4];
    T[r][c4] = v.x; T[r][c4 + 1] = v.y; T[r][c4 + 2] = v.z; T[r][c4 + 3] = v.w;
    __syncthreads();
    union { ushort s[4]; unsigned long long u; } o;
    o.s[0] = f2bf(T[c4 + 0][r]);
    o.s[1] = f2bf(T[c4 + 1][r]);
    o.s[2] = f2bf(T[c4 + 2][r]);
    o.s[3] = f2bf(T[c4 + 3][r]);
    *(unsigned long long*)&Wt[(size_t)(n0 + r) * K + k0 + c4] = o.u;
}

__global__ __launch_bounds__(256) void prep(
    const float* __restrict__ x, ushort* __restrict__ xb,
    const float* __restrict__ Wqkv, ushort* __restrict__ Wqkvt,
    const float* __restrict__ Wproj, ushort* __restrict__ Wprojt)
{
    const int bid = blockIdx.x, t = threadIdx.x;
    if (bid < 3072) {
        int i = bid * 256 + t;
        const float4* p = (const float4*)x + 2 * (size_t)i;
        float4 a = p[0], bq = p[1];
        union { ushort s[8]; uint4 v; } u;
        u.s[0] = f2bf(a.x);  u.s[1] = f2bf(a.y);  u.s[2] = f2bf(a.z);  u.s[3] = f2bf(a.w);
        u.s[4] = f2bf(bq.x); u.s[5] = f2bf(bq.y); u.s[6] = f2bf(bq.z); u.s[7] = f2bf(bq.w);
        *(uint4*)&xb[(size_t)i * 8] = u.v;
    } else if (bid < 4800) {
        int id = bid - 3072;                    // 72 x 24
        tr_body(Wqkv, Wqkvt, C_, 3 * C_, id % 72, id / 72, t);
    } else {
        int id = bid - 4800;                    // 24 x 24
        tr_body(Wproj, Wprojt, C_, C_, id % 24, id / 24, t);
    }
}

// ---------- bf16 MFMA GEMM: A[M][K] bf16, Bt[N][K] bf16, +bias ----------
// Tile 128(M) x TN(N), BK=64 single-buffered, 4 waves each 64 x TN/2.
// TN=192 for the QKV GEMM: grid = 12x64 = 768 blocks = exactly 3/CU, all
// co-resident, no straggler tail (measured WIN R16: total 225->210 us).
// launch_bounds(256,3) caps VGPR at 170 so 3 blocks/CU fit. TN=128 for the
// proj GEMM (measured: its balance doesn't matter). XCD-aware swizzle.
// OBF (qkv path): bf16 output, q-zone cols scaled by SC_LOG2E; v-zone cols
// (col0 >= 2C) are written TRANSPOSED per head into vtp[bh][d][tok].
template <bool OBF, int TN>
__global__ __launch_bounds__(256, 3) void gemm_bf16(
    const ushort* __restrict__ A, const ushort* __restrict__ Bt,
    const float* __restrict__ bias, void* __restrict__ outp,
    ushort* __restrict__ vtp,
    int M, int N, int K)
{
    constexpr int NTC = TN / 32;          // nt-count per wave (6 or 4)
    __shared__ ushort Asl[128 * 64];
    __shared__ ushort Bsl[TN * 64];

    const int tid  = threadIdx.x;
    const int lane = tid & 63, w = tid >> 6;
    const int quad = lane >> 4, l16 = lane & 15;

    // XCD swizzle: nwg % 8 == 0 for all launches (768, 384).
    const int nx   = gridDim.x;
    const int flat = blockIdx.y * nx + blockIdx.x;
    const int cpx  = (nx * gridDim.y) >> 3;
    const int nf   = (flat & 7) * cpx + (flat >> 3);
    const int row0 = (nf / nx) * 128, col0 = (nf % nx) * TN;
    const int mh = (w >> 1) * 64, nh = (w & 1) * (TN / 2);

    f32x4 acc[4][NTC];
#pragma unroll
    for (int i = 0; i < 4; i++)
#pragma unroll
        for (int j = 0; j < NTC; j++) acc[i][j] = (f32x4)0.f;

    for (int k0 = 0; k0 < K; k0 += 64) {
#pragma unroll
        for (int i = 0; i < 4; i++) {       // A: 1024 chunks
            int c  = i * 256 + w * 64 + lane;
            int rr = c >> 3;
            int cc = (c & 7) ^ (rr & 7);
            gl_lds16(&A[(size_t)(row0 + rr) * K + k0 + cc * 8], &Asl[c * 8]);
        }
#pragma unroll
        for (int i = 0; i < NTC; i++) {     // B: TN*8 chunks
            int c  = i * 256 + w * 64 + lane;
            int rr = c >> 3;
            int cc = (c & 7) ^ (rr & 7);
            gl_lds16(&Bt[(size_t)(col0 + rr) * K + k0 + cc * 8], &Bsl[c * 8]);
        }
        __syncthreads();
#pragma unroll
        for (int h = 0; h < 2; h++) {
            const int sw = ((h * 4 + quad) ^ (l16 & 7)) * 8;
            bf16x8 af[4], bfr[NTC];
#pragma unroll
            for (int mt = 0; mt < 4; mt++)
                af[mt] = *(const bf16x8*)&Asl[(mh + mt * 16 + l16) * 64 + sw];
#pragma unroll
            for (int nt = 0; nt < NTC; nt++)
                bfr[nt] = *(const bf16x8*)&Bsl[(nh + nt * 16 + l16) * 64 + sw];
#pragma unroll
            for (int mt = 0; mt < 4; mt++)
#pragma unroll
                for (int nt = 0; nt < NTC; nt++)
                    acc[mt][nt] = MFMA16(af[mt], bfr[nt], acc[mt][nt]);
        }
        __syncthreads();
    }

    if (OBF && col0 >= 2 * C_) {
        // v-zone: write transposed into Vt[bh][d][tok]
#pragma unroll
        for (int nt = 0; nt < NTC; nt++) {
            int colh = col0 - 2 * C_ + nh + nt * 16 + l16;   // 0..767
            int hh = colh >> 6, dd = colh & 63;
            float bv = bias[col0 + nh + nt * 16 + l16];
#pragma unroll
            for (int mt = 0; mt < 4; mt++) {
                f32x4 v = acc[mt][nt];
                int row = row0 + mh + mt * 16 + quad * 4;
                int bb = row >> 11, tok = row & (N_ - 1);
                union { ushort us[4]; unsigned long long u; } o;
#pragma unroll
                for (int r = 0; r < 4; r++) o.us[r] = f2bf(v[r] + bv);
                *(unsigned long long*)&vtp[((size_t)(bb * H_ + hh) * D_ + dd) * N_ + tok] = o.u;
            }
        }
    } else {
        const float scl = (OBF && col0 < C_) ? SC_LOG2E : 1.f;
#pragma unroll
        for (int nt = 0; nt < NTC; nt++) {
            int col = col0 + nh + nt * 16 + l16;
            float bv = bias[col];
#pragma unroll
            for (int mt = 0; mt < 4; mt++) {
                f32x4 v = acc[mt][nt];
#pragma unroll
                for (int r = 0; r < 4; r++) {
                    int row = row0 + mh + mt * 16 + quad * 4 + r;
                    if (OBF)
                        ((ushort*)outp)[(size_t)row * N + col] = f2bf((v[r] + bv) * scl);
                    else
                        ((float*)outp)[(size_t)row * N + col] = v[r] + bv;
                }
            }
        }
    }
}

// ---------- MFMA flash attention: 8 waves x 16 q, reg-P, triple-buffered ----------
// Measured best (R12/R16: 80-84 us; MfmaUtil ~40 + VALU ~52 = mixed-pipe
// floor; V-read bank pattern floor-optimal for ds_read_b64; scalar-store
// epilogue measured equal to LDS-transposed vectorized variant, R17).
__global__ __launch_bounds__(512, 6) void attn_mfma(
    const ushort* __restrict__ qkvb, const ushort* __restrict__ Vt,
    ushort* __restrict__ attnb)
{
    __shared__ ushort Kd[3][64 * 64];     // [key][d], swizzled 16B chunks
    __shared__ ushort Vd[3][64 * 64];     // [d][key], swizzled 16B chunks

    const int tid  = threadIdx.x;
    const int lane = tid & 63, w = tid >> 6;      // w = 0..7
    const int quad = lane >> 4, l16 = lane & 15;

    // XCD-aware remap (bijective: 768 % 8 == 0): each XCD gets 6 whole
    // heads (3 MB K/V working set, L2-resident).
    const int flat = blockIdx.y * 16 + blockIdx.x;
    const int nf   = (flat & 7) * 96 + (flat >> 3);
    const int bh   = nf >> 4, qt_ = nf & 15;
    const int b = bh / H_, h = bh % H_;
    const int q0 = qt_ * 128 + w * 16;
    const size_t rowbase = (size_t)b * N_;
    const int hoff = h * D_;
    const f32x4 Z4 = {0.f, 0.f, 0.f, 0.f};

    const ushort* Kg = qkvb + rowbase * (3 * C_) + C_ + hoff;  // + tok*(3C)
    const ushort* Vg = Vt + (size_t)bh * D_ * N_;              // + d*N_ + tok

    // staging: 512 threads cover the 512 16B-chunks of one 64x64 tile
    const int rr = tid >> 3;                  // row 0..63
    const int cc = (tid & 7) ^ (rr & 7);      // pre-swizzled chunk
    const int wbase = w * 512;                // wave-uniform LDS base (ushorts)
    const ushort* kp = Kg + (size_t)rr * (3 * C_) + cc * 8;
    const ushort* vp = Vg + (size_t)rr * N_ + cc * 8;

    bf16x8 Qf[2];
#pragma unroll
    for (int c = 0; c < 2; c++)
        Qf[c] = *(const bf16x8*)&qkvb[(rowbase + q0 + l16) * (3 * C_)
                                      + hoff + c * 32 + quad * 8];

    f32x4 oacc[4];
#pragma unroll
    for (int nt = 0; nt < 4; nt++) oacc[nt] = (f32x4)0.f;
    float lrow = 0.f;

    const int NT = N_ / 64;   // 32 tiles
    // prologue: stage tiles 0 and 1
    gl_lds16(kp, &Kd[0][wbase]);
    gl_lds16(vp, &Vd[0][wbase]);
    kp += (size_t)64 * 3 * C_; vp += 64;
    gl_lds16(kp, &Kd[1][wbase]);
    gl_lds16(vp, &Vd[1][wbase]);
    kp += (size_t)64 * 3 * C_; vp += 64;
    asm volatile("s_waitcnt vmcnt(2)" ::: "memory");   // tile 0 landed (mine)
    __builtin_amdgcn_s_barrier();                      // ...and everyone's
    __builtin_amdgcn_sched_barrier(0);

    int rd = 0;                                // read buffer = t % 3
    for (int t = 0; t < NT; ++t) {
        int wr = rd + 2; if (wr >= 3) wr -= 3; // (t+2) % 3
        if (t + 2 < NT) {
            gl_lds16(kp, &Kd[wr][wbase]);
            gl_lds16(vp, &Vd[wr][wbase]);
            kp += (size_t)64 * 3 * C_; vp += 64;
        }
        __builtin_amdgcn_sched_barrier(0);     // keep the issues early

        const ushort* Kb = Kd[rd];
        const ushort* Vb = Vd[rd];

        // QK^T: sacc[kt], lane holds P[key=kt*16+quad*4+r][q=l16]
        f32x4 sacc[4];
        {
            bf16x8 kf[4];
#pragma unroll
            for (int kt = 0; kt < 4; kt++)
                kf[kt] = *(const bf16x8*)&Kb[(kt * 16 + l16) * 64
                                             + ((quad) ^ (l16 & 7)) * 8];
            __builtin_amdgcn_s_setprio(1);
#pragma unroll
            for (int kt = 0; kt < 4; kt++)
                sacc[kt] = MFMA16(kf[kt], Qf[0], Z4);
            __builtin_amdgcn_s_setprio(0);
        }
        {
            bf16x8 kf[4];
#pragma unroll
            for (int kt = 0; kt < 4; kt++)
                kf[kt] = *(const bf16x8*)&Kb[(kt * 16 + l16) * 64
                                             + ((4 | quad) ^ (l16 & 7)) * 8];
            __builtin_amdgcn_s_setprio(1);
#pragma unroll
            for (int kt = 0; kt < 4; kt++)
                sacc[kt] = MFMA16(kf[kt], Qf[1], sacc[kt]);
            __builtin_amdgcn_s_setprio(0);
        }

        // softmax numerator -> packed bf16 pairs, kept in registers
        unsigned pkx[4], pky[4];
        {
            float sum = 0.f;
#pragma unroll
            for (int kt = 0; kt < 4; kt++) {
                float p0 = EXP2F(sacc[kt][0]);
                float p1 = EXP2F(sacc[kt][1]);
                float p2 = EXP2F(sacc[kt][2]);
                float p3 = EXP2F(sacc[kt][3]);
                sum += (p0 + p1) + (p2 + p3);
                pkx[kt] = pack_bf2(p0, p1);
                pky[kt] = pack_bf2(p2, p3);
            }
            lrow += sum;
        }

        // PV via 16x16x16: A = packed P (reg-direct), B = V^T 4-key b64.
        // out: lane holds O[q=quad*4+r][d=nt*16+l16] accumulated in oacc[nt].
        __builtin_amdgcn_s_setprio(1);
#pragma unroll
        for (int kt = 0; kt < 4; kt++) {
            union { unsigned u[2]; bf16x4 s; } av;
            av.u[0] = pkx[kt]; av.u[1] = pky[kt];
            const int ch = ((kt * 2 + (quad >> 1)) ^ (l16 & 7));
#pragma unroll
            for (int nt = 0; nt < 4; nt++) {
                bf16x4 vb = *(const bf16x4*)&Vb[(nt * 16 + l16) * 64
                                                + ch * 8 + (quad & 1) * 4];
                oacc[nt] = MFMA16K16(av.s, vb, oacc[nt]);
            }
        }
        __builtin_amdgcn_s_setprio(0);

        // counted wait: my t+1 loads have landed; t+2 stays in flight.
        if (t < NT - 2) asm volatile("s_waitcnt vmcnt(2)" ::: "memory");
        else            asm volatile("s_waitcnt vmcnt(0)" ::: "memory");
        __builtin_amdgcn_s_barrier();
        __builtin_amdgcn_sched_barrier(0);
        rd++; if (rd == 3) rd = 0;
    }

    {
        float s = lrow;
        s += __shfl_xor(s, 16, 64);
        s += __shfl_xor(s, 32, 64);          // lane L: denom for q = L&15
        float invq[4];
#pragma unroll
        for (int r = 0; r < 4; r++)
            invq[r] = 1.f / __shfl(s, quad * 4 + r, 64);
#pragma unroll
        for (int nt = 0; nt < 4; nt++) {
#pragma unroll
            for (int r = 0; r < 4; r++) {
                size_t orow = (rowbase + q0 + quad * 4 + r) * C_ + hoff;
                attnb[orow + nt * 16 + l16] = f2bf(oacc[nt][r] * invq[r]);
            }
        }
    }
}

// ---------------- launcher ----------------
extern "C" void kernel_launch(void* const* d_in, const int* in_sizes, int n_in,
                              void* d_out, int out_size, void* d_ws, size_t ws_size,
                              hipStream_t stream)
{
    const float* x     = (const float*)d_in[0];
    const float* Wqkv  = (const float*)d_in[1];
    const float* bqkv  = (const float*)d_in[2];
    const float* Wproj = (const float*)d_in[3];
    const float* bproj = (const float*)d_in[4];

    ushort* xb     = (ushort*)d_ws;                                    // [8192][768]
    ushort* Wqkvt  = xb + (size_t)B_ * N_ * C_;                        // [2304][768]
    ushort* Wprojt = Wqkvt + (size_t)3 * C_ * C_;                      // [768][768]
    ushort* qkvb   = Wprojt + (size_t)C_ * C_;                         // [8192][2304]
    ushort* attnb  = qkvb + (size_t)B_ * N_ * 3 * C_;                  // [8192][768]
    ushort* Vtb    = attnb + (size_t)B_ * N_ * C_;                     // [48][64][2048]

    const int M = B_ * N_;

    prep<<<5376, 256, 0, stream>>>(x, xb, Wqkv, Wqkvt, Wproj, Wprojt);

    gemm_bf16<true, 192><<<dim3((3 * C_) / 192, M / 128), 256, 0, stream>>>(
        xb, Wqkvt, bqkv, qkvb, Vtb, M, 3 * C_, C_);

    attn_mfma<<<dim3(N_ / 128, B_ * H_), 512, 0, stream>>>(qkvb, Vtb, attnb);

    gemm_bf16<false, 128><<<dim3(C_ / 128, M / 128), 256, 0, stream>>>(
        attnb, Wprojt, bproj, d_out, nullptr, M, C_, C_);
}